// Round 7
// baseline (142.072 us; speedup 1.0000x reference)
//
#include <hip/hip_runtime.h>
#include <math.h>

#define NP 8192
#define NF 16384
#define GQ 8
#define MARGIN 1e-5f   // f32 key abs-error bound ~1.5e-6; 6x safety
#define REPAIR_BLOCKS 64

#define FOR8(X) X(0) X(1) X(2) X(3) X(4) X(5) X(6) X(7)

// ---------------------------------------------------------------------------
// K0: face centers: f64 (cx,cy,cz,|c|^2) for exact d2/repair, f32 copy for
// the fast scan, Adagrad clr table, and zeroing of the repair counter.
// ---------------------------------------------------------------------------
__global__ __launch_bounds__(256) void k_centers(const float* __restrict__ mV,
                                                 const int* __restrict__ mF,
                                                 double* __restrict__ ctr,
                                                 float4* __restrict__ ctrf,
                                                 double* __restrict__ clrtab,
                                                 int* __restrict__ repair_cnt) {
    if (blockIdx.x == 0) {
        if (threadIdx.x < 50)
            clrtab[threadIdx.x] = 0.2 / (1.0 + (double)threadIdx.x * 0.1);
        if (threadIdx.x == 0) repair_cnt[0] = 0;
    }
    int f = blockIdx.x * 256 + threadIdx.x;
    if (f >= NF) return;
    int i0 = mF[3*f+0], i1 = mF[3*f+1], i2 = mF[3*f+2];
    double cx = ((double)mV[3*i0+0] + (double)mV[3*i1+0] + (double)mV[3*i2+0]) / 3.0;
    double cy = ((double)mV[3*i0+1] + (double)mV[3*i1+1] + (double)mV[3*i2+1]) / 3.0;
    double cz = ((double)mV[3*i0+2] + (double)mV[3*i1+2] + (double)mV[3*i2+2]) / 3.0;
    double cc = cx*cx + cy*cy + cz*cz;
    ctr[4*f+0] = cx; ctr[4*f+1] = cy; ctr[4*f+2] = cz; ctr[4*f+3] = cc;
    ctrf[f] = make_float4((float)cx, (float)cy, (float)cz, (float)cc);
}

// ---------------------------------------------------------------------------
// K1: f32 1-NN scan, top-2 tracked, ALL STATE IN NAMED SCALARS (round-6's
// [GQ] arrays were demoted to scratch: VGPR=36 < 48 live values needed).
// key = cc - 2 q.c; winner lex-min (key,idx); gap<MARGIN => repair list.
// Thread0: exact f64 d2 for winner -> outlier test -> outputs.
// ---------------------------------------------------------------------------
__global__ __launch_bounds__(256, 1) void k_knn(const float* __restrict__ qV,
                                                const float4* __restrict__ ctrf,
                                                const double* __restrict__ ctr,
                                                float* __restrict__ out,
                                                int* __restrict__ fidx_ws,
                                                int* __restrict__ valid_ws,
                                                int* __restrict__ repair_cnt,
                                                int* __restrict__ repair_list) {
    int pbase = blockIdx.x * GQ;

#define DECLQ(i) float qx##i = qV[3*(pbase+i)+0], \
                       qy##i = qV[3*(pbase+i)+1], \
                       qz##i = qV[3*(pbase+i)+2];
    FOR8(DECLQ)
#define DECLB(i) float b1_##i = 1e30f, b2_##i = 1e30f; int i1_##i = 0x7fffffff;
    FOR8(DECLB)

    for (int f = threadIdx.x; f < NF; f += 256) {
        float4 c = ctrf[f];
#define UPD(i) { float dot_ = qx##i*c.x + qy##i*c.y + qz##i*c.z;            \
                 float key_ = c.w - 2.0f*dot_;                              \
                 float ob_  = b1_##i;                                       \
                 bool  lt_  = key_ < ob_;                                   \
                 b1_##i = lt_ ? key_ : ob_;                                 \
                 i1_##i = lt_ ? f : i1_##i;                                 \
                 float c2_ = lt_ ? ob_ : key_;                              \
                 b2_##i = c2_ < b2_##i ? c2_ : b2_##i; }
        FOR8(UPD)
    }
    // wave (64-lane) top-2 merge, lex (b1,i1) for the winner
    #pragma unroll
    for (int off = 32; off > 0; off >>= 1) {
#define RED(i) { float ob1_ = __shfl_down(b1_##i, off);                     \
                 int   oi1_ = __shfl_down(i1_##i, off);                     \
                 float ob2_ = __shfl_down(b2_##i, off);                     \
                 bool  win_ = (ob1_ < b1_##i) || (ob1_ == b1_##i && oi1_ < i1_##i); \
                 float lsr_ = win_ ? b1_##i : ob1_;                         \
                 b1_##i = win_ ? ob1_ : b1_##i;                             \
                 i1_##i = win_ ? oi1_ : i1_##i;                             \
                 float mb2_ = ob2_ < b2_##i ? ob2_ : b2_##i;                \
                 b2_##i = lsr_ < mb2_ ? lsr_ : mb2_; }
        FOR8(RED)
    }
    __shared__ float sv1[4][GQ], sv2[4][GQ];
    __shared__ int   si1[4][GQ];
    int wid = threadIdx.x >> 6, lane = threadIdx.x & 63;
    if (lane == 0) {
#define ST(i) sv1[wid][i] = b1_##i; si1[wid][i] = i1_##i; sv2[wid][i] = b2_##i;
        FOR8(ST)
    }
    __syncthreads();
    if (threadIdx.x == 0) {
        const double4* ctr4 = (const double4*)ctr;
        for (int g = 0; g < GQ; ++g) {
            float bv = sv1[0][g], r2 = sv2[0][g]; int bi = si1[0][g];
            for (int w2 = 1; w2 < 4; ++w2) {
                float ob1 = sv1[w2][g], ob2 = sv2[w2][g]; int oi1 = si1[w2][g];
                bool win = (ob1 < bv) || (ob1 == bv && oi1 < bi);
                float loser = win ? bv : ob1;
                bv = win ? ob1 : bv;
                bi = win ? oi1 : bi;
                float mb2 = ob2 < r2 ? ob2 : r2;
                r2 = loser < mb2 ? loser : mb2;
            }
            int p = pbase + g;
            if (r2 - bv < MARGIN) {
                int slot = atomicAdd(repair_cnt, 1);
                repair_list[slot] = p;
            }
            // exact np d2 for the winning face (f64)
            double4 c = ctr4[bi];
            double dqx = (double)qV[3*p+0], dqy = (double)qV[3*p+1], dqz = (double)qV[3*p+2];
            double dot = dqx*c.x + dqy*c.y + dqz*c.z;
            double qq  = dqx*dqx + dqy*dqy + dqz*dqz;
            double d2  = (qq - 2.0*dot) + c.w;
            int outlier = (d2 > 0.1) ? 1 : 0;
            fidx_ws[p]  = bi;
            valid_ws[p] = 1 - outlier;
            out[p]        = (float)bi;               // output 0: spt_fidx
            out[3*NP + p] = outlier ? 1.0f : 0.0f;   // output 2: outlier_mask
        }
    }
}

// ---------------------------------------------------------------------------
// K1b: exact f64 repair, grid-striding the compacted flagged list. Full
// f64-key rescan, lex (key,idx) — identical semantics to the all-f64 rounds.
// List order is atomic-nondeterministic but each repair is independent and
// deterministic -> final outputs deterministic.
// ---------------------------------------------------------------------------
__global__ __launch_bounds__(256) void k_repair(const float* __restrict__ qV,
                                                const double* __restrict__ ctr,
                                                const int* __restrict__ repair_cnt,
                                                const int* __restrict__ repair_list,
                                                float* __restrict__ out,
                                                int* __restrict__ fidx_ws,
                                                int* __restrict__ valid_ws) {
    __shared__ double sv[4];
    __shared__ int    si[4];
    int n = repair_cnt[0];
    const double4* ctr4 = (const double4*)ctr;
    int wid = threadIdx.x >> 6, lane = threadIdx.x & 63;
    for (int idx = blockIdx.x; idx < n; idx += gridDim.x) {
        int p = repair_list[idx];
        double qx = (double)qV[3*p+0], qy = (double)qV[3*p+1], qz = (double)qV[3*p+2];
        double best = 1e300; int bidx = 0x7fffffff;
        for (int f = threadIdx.x; f < NF; f += 256) {
            double4 c = ctr4[f];
            double dot = qx*c.x + qy*c.y + qz*c.z;
            double key = c.w - 2.0*dot;
            if (key < best) { best = key; bidx = f; }   // ascending f: strict < = lex
        }
        #pragma unroll
        for (int off = 32; off > 0; off >>= 1) {
            double ov = __shfl_down(best, off);
            int    oi = __shfl_down(bidx, off);
            if (ov < best || (ov == best && oi < bidx)) { best = ov; bidx = oi; }
        }
        if (lane == 0) { sv[wid] = best; si[wid] = bidx; }
        __syncthreads();
        if (threadIdx.x == 0) {
            double bv = sv[0]; int bi = si[0];
            for (int w2 = 1; w2 < 4; ++w2) {
                double ov = sv[w2]; int oi = si[w2];
                if (ov < bv || (ov == bv && oi < bi)) { bv = ov; bi = oi; }
            }
            double4 c = ctr4[bi];
            double dot = qx*c.x + qy*c.y + qz*c.z;
            double qq  = qx*qx + qy*qy + qz*qz;
            double d2  = (qq - 2.0*dot) + c.w;
            int outlier = (d2 > 0.1) ? 1 : 0;
            fidx_ws[p]  = bi;
            valid_ws[p] = 1 - outlier;
            out[p]        = (float)bi;
            out[3*NP + p] = outlier ? 1.0f : 0.0f;
        }
        __syncthreads();
    }
}

// ---------------------------------------------------------------------------
// K2: denom = max(#valid, 1)
// ---------------------------------------------------------------------------
__global__ __launch_bounds__(256) void k_denom(const int* __restrict__ valid_ws,
                                               double* __restrict__ denom) {
    __shared__ int s[256];
    int acc = 0;
    for (int i = threadIdx.x; i < NP; i += 256) acc += valid_ws[i];
    s[threadIdx.x] = acc;
    __syncthreads();
    for (int off = 128; off > 0; off >>= 1) {
        if (threadIdx.x < off) s[threadIdx.x] += s[threadIdx.x + off];
        __syncthreads();
    }
    if (threadIdx.x == 0) {
        double d = (double)s[0];
        denom[0] = d > 1.0 ? d : 1.0;
    }
}

// ---------------------------------------------------------------------------
// K3: per-point 2x50-step Adagrad — BIT-IDENTICAL to the round-4 passing
// version (slim vw margin; do not perturb).
// ---------------------------------------------------------------------------
__global__ __launch_bounds__(256) void k_opt(const float* __restrict__ qV,
                                             const float* __restrict__ qN,
                                             const float* __restrict__ mV,
                                             const int* __restrict__ mF,
                                             const float* __restrict__ mN,
                                             const int* __restrict__ fidx_ws,
                                             const int* __restrict__ valid_ws,
                                             const double* __restrict__ denomp,
                                             const double* __restrict__ clrtab,
                                             float* __restrict__ out) {
    int p = blockIdx.x * 256 + threadIdx.x;
    if (p >= NP) return;
    const float third = (float)(1.0/3.0);
    if (!valid_ws[p]) {            // outlier: keeps init barycentric coords
        out[NP + 2*p + 0] = third;
        out[NP + 2*p + 1] = third;
        return;
    }
    double inv_denom = 1.0 / denomp[0];
    int f = fidx_ws[p];
    int i0 = mF[3*f+0], i1 = mF[3*f+1], i2 = mF[3*f+2];

    double V0x = mV[3*i0+0], V0y = mV[3*i0+1], V0z = mV[3*i0+2];
    double V1x = mV[3*i1+0], V1y = mV[3*i1+1], V1z = mV[3*i1+2];
    double V2x = mV[3*i2+0], V2y = mV[3*i2+1], V2z = mV[3*i2+2];
    double N0x = mN[3*i0+0], N0y = mN[3*i0+1], N0z = mN[3*i0+2];
    double N1x = mN[3*i1+0], N1y = mN[3*i1+1], N1z = mN[3*i1+2];
    double N2x = mN[3*i2+0], N2y = mN[3*i2+1], N2z = mN[3*i2+2];
    double qx  = qV[3*p+0],  qy  = qV[3*p+1],  qz  = qV[3*p+2];
    double qnx = qN[3*p+0],  qny = qN[3*p+1],  qnz = qN[3*p+2];

    double Eux = V0x - V2x, Euy = V0y - V2y, Euz = V0z - V2z;  // dcV/du
    double Ewx = V1x - V2x, Ewy = V1y - V2y, Ewz = V1z - V2z;  // dcV/dw
    double Fux = N0x - N2x, Fuy = N0y - N2y, Fuz = N0z - N2z;  // dn_raw/du
    double Fwx = N1x - N2x, Fwy = N1y - N2y, Fwz = N1z - N2z;  // dn_raw/dw
    double Kx  = V2x - qx,  Ky  = V2y - qy,  Kz  = V2z - qz;   // cv - q at uu=ww=0

    double u = 1.0/3.0, w = 1.0/3.0;
    double alpha = 1.0;
    for (int outer = 0; outer < 2; ++outer) {
        double du = 0.0, dw = 0.0, su = 0.0, sw = 0.0;
        for (int it = 0; it < 50; ++it) {
            double uu = u + du, ww = w + dw;
            // position term: rv = cv - q = uu*Eu + ww*Ew + K
            double rvx = uu*Eux + ww*Ewx + Kx;
            double rvy = uu*Euy + ww*Ewy + Ky;
            double rvz = uu*Euz + ww*Ewz + Kz;
            double L2v = rvx*rvx + rvy*rvy + rvz*rvz;
            double invLv = rsqrt(L2v);
            double gu = (rvx*Eux + rvy*Euy + rvz*Euz) * invLv;
            double gw = (rvx*Ewx + rvy*Ewy + rvz*Ewz) * invLv;
            // normal term: n = uu*Fu + ww*Fw + N2
            double nx = uu*Fux + ww*Fwx + N2x;
            double ny = uu*Fuy + ww*Fwy + N2y;
            double nz = uu*Fuz + ww*Fwz + N2z;
            double m2 = nx*nx + ny*ny + nz*nz;
            bool   mok = (m2 > 1e-24);           // <=> m > 1e-12
            double inv = mok ? rsqrt(m2) : 1e12; // 1/max(m,1e-12)
            double hx = nx*inv, hy = ny*inv, hz = nz*inv;
            double rnx = hx - qnx, rny = hy - qny, rnz = hz - qnz;
            double L2n = rnx*rnx + rny*rny + rnz*rnz;
            double invLn = rsqrt(L2n);
            double A_u = rnx*Fux + rny*Fuy + rnz*Fuz;
            double A_w = rnx*Fwx + rny*Fwy + rnz*Fwz;
            double B   = rnx*nx + rny*ny + rnz*nz;
            double C_u = nx*Fux + ny*Fuy + nz*Fuz;
            double C_w = nx*Fwx + ny*Fwy + nz*Fwz;
            // s = B/m^3 when m > eps else 0 (original dropped the term there)
            double s = mok ? ((B*inv)*inv)*inv : 0.0;
            double gnu = (A_u*inv - s*C_u) * invLn;
            double gnw = (A_w*inv - s*C_w) * invLn;
            gu = (gu + 0.01*gnu) * inv_denom;   // mask=1, masked-mean scaling
            gw = (gw + 0.01*gnw) * inv_denom;
            // Adagrad(lr=0.2, lr_decay=0.1)
            su += gu*gu; sw += gw*gw;
            double clr = clrtab[it];
            du -= clr * gu / (sqrt(su) + 1e-10);
            dw -= clr * gw / (sqrt(sw) + 1e-10);
        }
        u += du * alpha; w += dw * alpha;
        alpha *= 0.5;
    }
    out[NP + 2*p + 0] = (float)u;
    out[NP + 2*p + 1] = (float)w;
}

// ---------------------------------------------------------------------------
extern "C" void kernel_launch(void* const* d_in, const int* in_sizes, int n_in,
                              void* d_out, int out_size, void* d_ws, size_t ws_size,
                              hipStream_t stream) {
    const float* qV = (const float*)d_in[0];   // query_V [1,8192,3]
    const float* qN = (const float*)d_in[1];   // query_N [1,8192,3]
    const float* mV = (const float*)d_in[2];   // mesh_V  [16384,3]
    const int*   mF = (const int*)d_in[3];     // mesh_F  [16384,3] int32
    const float* mN = (const float*)d_in[4];   // mesh_N  [16384,3]
    float* out = (float*)d_out;                // fidx | vw | outlier_mask

    double* ctr        = (double*)d_ws;             // NF*4 doubles (512 KB)
    double* denom      = ctr + (size_t)NF*4;        // 1 double
    double* clrtab     = denom + 1;                 // 50 doubles
    float4* ctrf       = (float4*)(clrtab + 50);    // NF float4 (256 KB)
    int*    repair_cnt = (int*)(ctrf + NF);         // 1 int
    int*    repair_list= repair_cnt + 1;            // NP ints
    int*    fidx_ws    = repair_list + NP;          // NP ints
    int*    valid_ws   = fidx_ws + NP;              // NP ints

    hipLaunchKernelGGL(k_centers, dim3(NF/256), dim3(256), 0, stream,
                       mV, mF, ctr, ctrf, clrtab, repair_cnt);
    hipLaunchKernelGGL(k_knn,     dim3(NP/GQ),  dim3(256), 0, stream, qV, ctrf, ctr,
                       out, fidx_ws, valid_ws, repair_cnt, repair_list);
    hipLaunchKernelGGL(k_repair,  dim3(REPAIR_BLOCKS), dim3(256), 0, stream,
                       qV, ctr, repair_cnt, repair_list, out, fidx_ws, valid_ws);
    hipLaunchKernelGGL(k_denom,   dim3(1),      dim3(256), 0, stream, valid_ws, denom);
    hipLaunchKernelGGL(k_opt,     dim3(NP/256), dim3(256), 0, stream,
                       qV, qN, mV, mF, mN, fidx_ws, valid_ws, denom, clrtab, out);
}

// Round 8
// 104.832 us; speedup vs baseline: 1.3552x; 1.3552x over previous
//
#include <hip/hip_runtime.h>
#include <math.h>

#define NP 8192
#define NF 16384
#define GQ 8
#define SPLIT 2
#define NFS (NF / SPLIT)   // faces per split = 8192
#define NG (NP / GQ)       // point groups = 1024

// ---------------------------------------------------------------------------
// K0: face centers in f64 + |c|^2 (np: c=(v0+v1+v2)/3), plus Adagrad clr table
// ---------------------------------------------------------------------------
__global__ __launch_bounds__(256) void k_centers(const float* __restrict__ mV,
                                                 const int* __restrict__ mF,
                                                 double* __restrict__ ctr,
                                                 double* __restrict__ clrtab) {
    if (blockIdx.x == 0 && threadIdx.x < 50) {
        clrtab[threadIdx.x] = 0.2 / (1.0 + (double)threadIdx.x * 0.1);
    }
    int f = blockIdx.x * 256 + threadIdx.x;
    if (f >= NF) return;
    int i0 = mF[3*f+0], i1 = mF[3*f+1], i2 = mF[3*f+2];
    double cx = ((double)mV[3*i0+0] + (double)mV[3*i1+0] + (double)mV[3*i2+0]) / 3.0;
    double cy = ((double)mV[3*i0+1] + (double)mV[3*i1+1] + (double)mV[3*i2+1]) / 3.0;
    double cz = ((double)mV[3*i0+2] + (double)mV[3*i1+2] + (double)mV[3*i2+2]) / 3.0;
    ctr[4*f+0] = cx; ctr[4*f+1] = cy; ctr[4*f+2] = cz;
    ctr[4*f+3] = cx*cx + cy*cy + cz*cz;
}

// ---------------------------------------------------------------------------
// K1a: partial f64 1-NN. Block = (group g, split s); scans [s*NFS,(s+1)*NFS).
// EXACTLY the proven round-2/3 scan body (GQ=8 f64, no spill) at half the
// per-block face count; SPLIT=2 doubles resident waves (the round-3 scan was
// occupancy-capped at 1024 blocks). key = cc - 2 q.c; lex (key,idx) is
// order-independent -> outputs provably identical to rounds 2-7.
// ---------------------------------------------------------------------------
__global__ __launch_bounds__(256) void k_knn_part(const float* __restrict__ qV,
                                                  const double* __restrict__ ctr,
                                                  double* __restrict__ pkey,
                                                  int* __restrict__ pidx) {
    int g = blockIdx.x / SPLIT;
    int s = blockIdx.x % SPLIT;
    int pbase = g * GQ;
    int fbase = s * NFS;

    double qx[GQ], qy[GQ], qz[GQ];
    #pragma unroll
    for (int gg = 0; gg < GQ; ++gg) {
        int p = pbase + gg;
        qx[gg] = (double)qV[3*p+0];
        qy[gg] = (double)qV[3*p+1];
        qz[gg] = (double)qV[3*p+2];
    }
    double best[GQ]; int bidx[GQ];
    #pragma unroll
    for (int gg = 0; gg < GQ; ++gg) { best[gg] = 1e300; bidx[gg] = 0x7fffffff; }

    const double4* ctr4 = (const double4*)ctr;
    #pragma unroll 2
    for (int fo = threadIdx.x; fo < NFS; fo += 256) {
        int f = fbase + fo;
        double4 c = ctr4[f];
        #pragma unroll
        for (int gg = 0; gg < GQ; ++gg) {
            double dot = qx[gg]*c.x + qy[gg]*c.y + qz[gg]*c.z;
            double key = c.w - 2.0*dot;
            if (key < best[gg]) { best[gg] = key; bidx[gg] = f; }  // f ascends: < = lex
        }
    }
    // wave (64-lane) reduction, lexicographic (key, idx)
    #pragma unroll
    for (int off = 32; off > 0; off >>= 1) {
        #pragma unroll
        for (int gg = 0; gg < GQ; ++gg) {
            double ov = __shfl_down(best[gg], off);
            int    oi = __shfl_down(bidx[gg], off);
            if (ov < best[gg] || (ov == best[gg] && oi < bidx[gg])) { best[gg] = ov; bidx[gg] = oi; }
        }
    }
    __shared__ double sv[4][GQ];
    __shared__ int    si[4][GQ];
    int wid = threadIdx.x >> 6, lane = threadIdx.x & 63;
    if (lane == 0) {
        #pragma unroll
        for (int gg = 0; gg < GQ; ++gg) { sv[wid][gg] = best[gg]; si[wid][gg] = bidx[gg]; }
    }
    __syncthreads();
    if (threadIdx.x == 0) {
        for (int gg = 0; gg < GQ; ++gg) {
            double bv = sv[0][gg]; int bi = si[0][gg];
            for (int w2 = 1; w2 < 4; ++w2) {
                double ov = sv[w2][gg]; int oi = si[w2][gg];
                if (ov < bv || (ov == bv && oi < bi)) { bv = ov; bi = oi; }
            }
            int slot = (g * SPLIT + s) * GQ + gg;
            pkey[slot] = bv;
            pidx[slot] = bi;
        }
    }
}

// ---------------------------------------------------------------------------
// K1b: per point, lex-merge the SPLIT partials, exact np d2 for the winner,
// outlier test, final fidx/mask outputs. (Proven in round 5: identical absmax.)
// ---------------------------------------------------------------------------
__global__ __launch_bounds__(256) void k_finish(const float* __restrict__ qV,
                                                const double* __restrict__ ctr,
                                                const double* __restrict__ pkey,
                                                const int* __restrict__ pidx,
                                                float* __restrict__ out,
                                                int* __restrict__ fidx_ws,
                                                int* __restrict__ valid_ws) {
    int p = blockIdx.x * 256 + threadIdx.x;
    if (p >= NP) return;
    int g = p / GQ, j = p % GQ;
    double bv = 1e300; int bi = 0x7fffffff;
    #pragma unroll
    for (int s = 0; s < SPLIT; ++s) {
        int slot = (g * SPLIT + s) * GQ + j;
        double ov = pkey[slot]; int oi = pidx[slot];
        if (ov < bv || (ov == bv && oi < bi)) { bv = ov; bi = oi; }
    }
    // exact np d2 for the winning face
    const double4* ctr4 = (const double4*)ctr;
    double4 c = ctr4[bi];
    double qx = (double)qV[3*p+0], qy = (double)qV[3*p+1], qz = (double)qV[3*p+2];
    double dot = qx*c.x + qy*c.y + qz*c.z;
    double qq  = qx*qx + qy*qy + qz*qz;
    double d2  = (qq - 2.0*dot) + c.w;
    int outlier = (d2 > 0.1) ? 1 : 0;
    fidx_ws[p]  = bi;
    valid_ws[p] = 1 - outlier;
    out[p]        = (float)bi;               // output 0: spt_fidx
    out[3*NP + p] = outlier ? 1.0f : 0.0f;   // output 2: outlier_mask
}

// ---------------------------------------------------------------------------
// K2: denom = max(#valid, 1)
// ---------------------------------------------------------------------------
__global__ __launch_bounds__(256) void k_denom(const int* __restrict__ valid_ws,
                                               double* __restrict__ denom) {
    __shared__ int s[256];
    int acc = 0;
    for (int i = threadIdx.x; i < NP; i += 256) acc += valid_ws[i];
    s[threadIdx.x] = acc;
    __syncthreads();
    for (int off = 128; off > 0; off >>= 1) {
        if (threadIdx.x < off) s[threadIdx.x] += s[threadIdx.x + off];
        __syncthreads();
    }
    if (threadIdx.x == 0) {
        double d = (double)s[0];
        denom[0] = d > 1.0 ? d : 1.0;
    }
}

// ---------------------------------------------------------------------------
// K3: per-point 2x50-step Adagrad — BIT-IDENTICAL to the round-4 passing
// version (slim vw margin; do not perturb).
// ---------------------------------------------------------------------------
__global__ __launch_bounds__(256) void k_opt(const float* __restrict__ qV,
                                             const float* __restrict__ qN,
                                             const float* __restrict__ mV,
                                             const int* __restrict__ mF,
                                             const float* __restrict__ mN,
                                             const int* __restrict__ fidx_ws,
                                             const int* __restrict__ valid_ws,
                                             const double* __restrict__ denomp,
                                             const double* __restrict__ clrtab,
                                             float* __restrict__ out) {
    int p = blockIdx.x * 256 + threadIdx.x;
    if (p >= NP) return;
    const float third = (float)(1.0/3.0);
    if (!valid_ws[p]) {            // outlier: keeps init barycentric coords
        out[NP + 2*p + 0] = third;
        out[NP + 2*p + 1] = third;
        return;
    }
    double inv_denom = 1.0 / denomp[0];
    int f = fidx_ws[p];
    int i0 = mF[3*f+0], i1 = mF[3*f+1], i2 = mF[3*f+2];

    double V0x = mV[3*i0+0], V0y = mV[3*i0+1], V0z = mV[3*i0+2];
    double V1x = mV[3*i1+0], V1y = mV[3*i1+1], V1z = mV[3*i1+2];
    double V2x = mV[3*i2+0], V2y = mV[3*i2+1], V2z = mV[3*i2+2];
    double N0x = mN[3*i0+0], N0y = mN[3*i0+1], N0z = mN[3*i0+2];
    double N1x = mN[3*i1+0], N1y = mN[3*i1+1], N1z = mN[3*i1+2];
    double N2x = mN[3*i2+0], N2y = mN[3*i2+1], N2z = mN[3*i2+2];
    double qx  = qV[3*p+0],  qy  = qV[3*p+1],  qz  = qV[3*p+2];
    double qnx = qN[3*p+0],  qny = qN[3*p+1],  qnz = qN[3*p+2];

    double Eux = V0x - V2x, Euy = V0y - V2y, Euz = V0z - V2z;  // dcV/du
    double Ewx = V1x - V2x, Ewy = V1y - V2y, Ewz = V1z - V2z;  // dcV/dw
    double Fux = N0x - N2x, Fuy = N0y - N2y, Fuz = N0z - N2z;  // dn_raw/du
    double Fwx = N1x - N2x, Fwy = N1y - N2y, Fwz = N1z - N2z;  // dn_raw/dw
    double Kx  = V2x - qx,  Ky  = V2y - qy,  Kz  = V2z - qz;   // cv - q at uu=ww=0

    double u = 1.0/3.0, w = 1.0/3.0;
    double alpha = 1.0;
    for (int outer = 0; outer < 2; ++outer) {
        double du = 0.0, dw = 0.0, su = 0.0, sw = 0.0;
        for (int it = 0; it < 50; ++it) {
            double uu = u + du, ww = w + dw;
            // position term: rv = cv - q = uu*Eu + ww*Ew + K
            double rvx = uu*Eux + ww*Ewx + Kx;
            double rvy = uu*Euy + ww*Ewy + Ky;
            double rvz = uu*Euz + ww*Ewz + Kz;
            double L2v = rvx*rvx + rvy*rvy + rvz*rvz;
            double invLv = rsqrt(L2v);
            double gu = (rvx*Eux + rvy*Euy + rvz*Euz) * invLv;
            double gw = (rvx*Ewx + rvy*Ewy + rvz*Ewz) * invLv;
            // normal term: n = uu*Fu + ww*Fw + N2
            double nx = uu*Fux + ww*Fwx + N2x;
            double ny = uu*Fuy + ww*Fwy + N2y;
            double nz = uu*Fuz + ww*Fwz + N2z;
            double m2 = nx*nx + ny*ny + nz*nz;
            bool   mok = (m2 > 1e-24);           // <=> m > 1e-12
            double inv = mok ? rsqrt(m2) : 1e12; // 1/max(m,1e-12)
            double hx = nx*inv, hy = ny*inv, hz = nz*inv;
            double rnx = hx - qnx, rny = hy - qny, rnz = hz - qnz;
            double L2n = rnx*rnx + rny*rny + rnz*rnz;
            double invLn = rsqrt(L2n);
            double A_u = rnx*Fux + rny*Fuy + rnz*Fuz;
            double A_w = rnx*Fwx + rny*Fwy + rnz*Fwz;
            double B   = rnx*nx + rny*ny + rnz*nz;
            double C_u = nx*Fux + ny*Fuy + nz*Fuz;
            double C_w = nx*Fwx + ny*Fwy + nz*Fwz;
            // s = B/m^3 when m > eps else 0 (original dropped the term there)
            double s = mok ? ((B*inv)*inv)*inv : 0.0;
            double gnu = (A_u*inv - s*C_u) * invLn;
            double gnw = (A_w*inv - s*C_w) * invLn;
            gu = (gu + 0.01*gnu) * inv_denom;   // mask=1, masked-mean scaling
            gw = (gw + 0.01*gnw) * inv_denom;
            // Adagrad(lr=0.2, lr_decay=0.1)
            su += gu*gu; sw += gw*gw;
            double clr = clrtab[it];
            du -= clr * gu / (sqrt(su) + 1e-10);
            dw -= clr * gw / (sqrt(sw) + 1e-10);
        }
        u += du * alpha; w += dw * alpha;
        alpha *= 0.5;
    }
    out[NP + 2*p + 0] = (float)u;
    out[NP + 2*p + 1] = (float)w;
}

// ---------------------------------------------------------------------------
extern "C" void kernel_launch(void* const* d_in, const int* in_sizes, int n_in,
                              void* d_out, int out_size, void* d_ws, size_t ws_size,
                              hipStream_t stream) {
    const float* qV = (const float*)d_in[0];   // query_V [1,8192,3]
    const float* qN = (const float*)d_in[1];   // query_N [1,8192,3]
    const float* mV = (const float*)d_in[2];   // mesh_V  [16384,3]
    const int*   mF = (const int*)d_in[3];     // mesh_F  [16384,3] int32
    const float* mN = (const float*)d_in[4];   // mesh_N  [16384,3]
    float* out = (float*)d_out;                // fidx | vw | outlier_mask

    double* ctr      = (double*)d_ws;               // NF*4 doubles (512 KB)
    double* denom    = ctr + (size_t)NF*4;          // 1 double
    double* clrtab   = denom + 1;                   // 50 doubles
    double* pkey     = clrtab + 50;                 // NP*SPLIT doubles (128 KB)
    int*    pidx     = (int*)(pkey + (size_t)NP*SPLIT);  // NP*SPLIT ints
    int*    fidx_ws  = pidx + (size_t)NP*SPLIT;          // NP ints
    int*    valid_ws = fidx_ws + NP;                     // NP ints

    hipLaunchKernelGGL(k_centers,  dim3(NF/256),   dim3(256), 0, stream, mV, mF, ctr, clrtab);
    hipLaunchKernelGGL(k_knn_part, dim3(NG*SPLIT), dim3(256), 0, stream, qV, ctr, pkey, pidx);
    hipLaunchKernelGGL(k_finish,   dim3(NP/256),   dim3(256), 0, stream, qV, ctr, pkey, pidx,
                       out, fidx_ws, valid_ws);
    hipLaunchKernelGGL(k_denom,    dim3(1),        dim3(256), 0, stream, valid_ws, denom);
    hipLaunchKernelGGL(k_opt,      dim3(NP/256),   dim3(256), 0, stream,
                       qV, qN, mV, mF, mN, fidx_ws, valid_ws, denom, clrtab, out);
}

// Round 9
// 104.769 us; speedup vs baseline: 1.3560x; 1.0006x over previous
//
#include <hip/hip_runtime.h>
#include <math.h>

#define NP 8192
#define NF 16384
#define GQ 8
#define SPLIT 2
#define NFS (NF / SPLIT)   // faces per split = 8192
#define NG (NP / GQ)       // point groups = 1024

// ---------------------------------------------------------------------------
// K0: face centers in f64 + |c|^2 (np: c=(v0+v1+v2)/3), plus Adagrad clr table
// ---------------------------------------------------------------------------
__global__ __launch_bounds__(256) void k_centers(const float* __restrict__ mV,
                                                 const int* __restrict__ mF,
                                                 double* __restrict__ ctr,
                                                 double* __restrict__ clrtab) {
    if (blockIdx.x == 0 && threadIdx.x < 50) {
        clrtab[threadIdx.x] = 0.2 / (1.0 + (double)threadIdx.x * 0.1);
    }
    int f = blockIdx.x * 256 + threadIdx.x;
    if (f >= NF) return;
    int i0 = mF[3*f+0], i1 = mF[3*f+1], i2 = mF[3*f+2];
    double cx = ((double)mV[3*i0+0] + (double)mV[3*i1+0] + (double)mV[3*i2+0]) / 3.0;
    double cy = ((double)mV[3*i0+1] + (double)mV[3*i1+1] + (double)mV[3*i2+1]) / 3.0;
    double cz = ((double)mV[3*i0+2] + (double)mV[3*i1+2] + (double)mV[3*i2+2]) / 3.0;
    ctr[4*f+0] = cx; ctr[4*f+1] = cy; ctr[4*f+2] = cz;
    ctr[4*f+3] = cx*cx + cy*cy + cz*cz;
}

// ---------------------------------------------------------------------------
// K1a: partial f64 1-NN — IDENTICAL ARITHMETIC to round 8 (provably same
// outputs). Codegen fixes only:
//   - __launch_bounds__(256,2): round-8's allocator targeted 8 waves/EU,
//     capped VGPR at 48 vs ~88 live values -> scratch spill in the hot loop.
//     Min-2-waves target lets it allocate ~90-120 (4 waves/SIMD, which fully
//     saturates the 4-cyc f64 issue pipe — occupancy beyond that is unneeded).
//   - one-ahead register prefetch of the next double4 (branchless & wrap)
//     to hide ~200cyc L2 latency under ~200cyc of per-iter f64 compute.
// ---------------------------------------------------------------------------
__global__ __launch_bounds__(256, 2) void k_knn_part(const float* __restrict__ qV,
                                                     const double* __restrict__ ctr,
                                                     double* __restrict__ pkey,
                                                     int* __restrict__ pidx) {
    int g = blockIdx.x / SPLIT;
    int s = blockIdx.x % SPLIT;
    int pbase = g * GQ;
    int fbase = s * NFS;

    double qx[GQ], qy[GQ], qz[GQ];
    #pragma unroll
    for (int gg = 0; gg < GQ; ++gg) {
        int p = pbase + gg;
        qx[gg] = (double)qV[3*p+0];
        qy[gg] = (double)qV[3*p+1];
        qz[gg] = (double)qV[3*p+2];
    }
    double best[GQ]; int bidx[GQ];
    #pragma unroll
    for (int gg = 0; gg < GQ; ++gg) { best[gg] = 1e300; bidx[gg] = 0x7fffffff; }

    const double4* ctr4 = (const double4*)ctr;
    int fo = threadIdx.x;
    double4 c = ctr4[fbase + fo];
    for (int it = 0; it < NFS/256; ++it) {
        // prefetch next tile (wraps harmlessly on the last iteration)
        double4 cn = ctr4[fbase + ((fo + 256) & (NFS - 1))];
        int f = fbase + fo;
        #pragma unroll
        for (int gg = 0; gg < GQ; ++gg) {
            double dot = qx[gg]*c.x + qy[gg]*c.y + qz[gg]*c.z;
            double key = c.w - 2.0*dot;
            if (key < best[gg]) { best[gg] = key; bidx[gg] = f; }  // f ascends: < = lex
        }
        c = cn;
        fo += 256;
    }
    // wave (64-lane) reduction, lexicographic (key, idx)
    #pragma unroll
    for (int off = 32; off > 0; off >>= 1) {
        #pragma unroll
        for (int gg = 0; gg < GQ; ++gg) {
            double ov = __shfl_down(best[gg], off);
            int    oi = __shfl_down(bidx[gg], off);
            if (ov < best[gg] || (ov == best[gg] && oi < bidx[gg])) { best[gg] = ov; bidx[gg] = oi; }
        }
    }
    __shared__ double sv[4][GQ];
    __shared__ int    si[4][GQ];
    int wid = threadIdx.x >> 6, lane = threadIdx.x & 63;
    if (lane == 0) {
        #pragma unroll
        for (int gg = 0; gg < GQ; ++gg) { sv[wid][gg] = best[gg]; si[wid][gg] = bidx[gg]; }
    }
    __syncthreads();
    if (threadIdx.x == 0) {
        for (int gg = 0; gg < GQ; ++gg) {
            double bv = sv[0][gg]; int bi = si[0][gg];
            for (int w2 = 1; w2 < 4; ++w2) {
                double ov = sv[w2][gg]; int oi = si[w2][gg];
                if (ov < bv || (ov == bv && oi < bi)) { bv = ov; bi = oi; }
            }
            int slot = (g * SPLIT + s) * GQ + gg;
            pkey[slot] = bv;
            pidx[slot] = bi;
        }
    }
}

// ---------------------------------------------------------------------------
// K1b: per point, lex-merge the SPLIT partials, exact np d2 for the winner,
// outlier test, final fidx/mask outputs. (Proven: identical absmax.)
// ---------------------------------------------------------------------------
__global__ __launch_bounds__(256) void k_finish(const float* __restrict__ qV,
                                                const double* __restrict__ ctr,
                                                const double* __restrict__ pkey,
                                                const int* __restrict__ pidx,
                                                float* __restrict__ out,
                                                int* __restrict__ fidx_ws,
                                                int* __restrict__ valid_ws) {
    int p = blockIdx.x * 256 + threadIdx.x;
    if (p >= NP) return;
    int g = p / GQ, j = p % GQ;
    double bv = 1e300; int bi = 0x7fffffff;
    #pragma unroll
    for (int s = 0; s < SPLIT; ++s) {
        int slot = (g * SPLIT + s) * GQ + j;
        double ov = pkey[slot]; int oi = pidx[slot];
        if (ov < bv || (ov == bv && oi < bi)) { bv = ov; bi = oi; }
    }
    // exact np d2 for the winning face
    const double4* ctr4 = (const double4*)ctr;
    double4 c = ctr4[bi];
    double qx = (double)qV[3*p+0], qy = (double)qV[3*p+1], qz = (double)qV[3*p+2];
    double dot = qx*c.x + qy*c.y + qz*c.z;
    double qq  = qx*qx + qy*qy + qz*qz;
    double d2  = (qq - 2.0*dot) + c.w;
    int outlier = (d2 > 0.1) ? 1 : 0;
    fidx_ws[p]  = bi;
    valid_ws[p] = 1 - outlier;
    out[p]        = (float)bi;               // output 0: spt_fidx
    out[3*NP + p] = outlier ? 1.0f : 0.0f;   // output 2: outlier_mask
}

// ---------------------------------------------------------------------------
// K2: denom = max(#valid, 1)
// ---------------------------------------------------------------------------
__global__ __launch_bounds__(256) void k_denom(const int* __restrict__ valid_ws,
                                               double* __restrict__ denom) {
    __shared__ int s[256];
    int acc = 0;
    for (int i = threadIdx.x; i < NP; i += 256) acc += valid_ws[i];
    s[threadIdx.x] = acc;
    __syncthreads();
    for (int off = 128; off > 0; off >>= 1) {
        if (threadIdx.x < off) s[threadIdx.x] += s[threadIdx.x + off];
        __syncthreads();
    }
    if (threadIdx.x == 0) {
        double d = (double)s[0];
        denom[0] = d > 1.0 ? d : 1.0;
    }
}

// ---------------------------------------------------------------------------
// K3: per-point 2x50-step Adagrad — BIT-IDENTICAL to the round-4 passing
// version (slim vw margin; do not perturb).
// ---------------------------------------------------------------------------
__global__ __launch_bounds__(256) void k_opt(const float* __restrict__ qV,
                                             const float* __restrict__ qN,
                                             const float* __restrict__ mV,
                                             const int* __restrict__ mF,
                                             const float* __restrict__ mN,
                                             const int* __restrict__ fidx_ws,
                                             const int* __restrict__ valid_ws,
                                             const double* __restrict__ denomp,
                                             const double* __restrict__ clrtab,
                                             float* __restrict__ out) {
    int p = blockIdx.x * 256 + threadIdx.x;
    if (p >= NP) return;
    const float third = (float)(1.0/3.0);
    if (!valid_ws[p]) {            // outlier: keeps init barycentric coords
        out[NP + 2*p + 0] = third;
        out[NP + 2*p + 1] = third;
        return;
    }
    double inv_denom = 1.0 / denomp[0];
    int f = fidx_ws[p];
    int i0 = mF[3*f+0], i1 = mF[3*f+1], i2 = mF[3*f+2];

    double V0x = mV[3*i0+0], V0y = mV[3*i0+1], V0z = mV[3*i0+2];
    double V1x = mV[3*i1+0], V1y = mV[3*i1+1], V1z = mV[3*i1+2];
    double V2x = mV[3*i2+0], V2y = mV[3*i2+1], V2z = mV[3*i2+2];
    double N0x = mN[3*i0+0], N0y = mN[3*i0+1], N0z = mN[3*i0+2];
    double N1x = mN[3*i1+0], N1y = mN[3*i1+1], N1z = mN[3*i1+2];
    double N2x = mN[3*i2+0], N2y = mN[3*i2+1], N2z = mN[3*i2+2];
    double qx  = qV[3*p+0],  qy  = qV[3*p+1],  qz  = qV[3*p+2];
    double qnx = qN[3*p+0],  qny = qN[3*p+1],  qnz = qN[3*p+2];

    double Eux = V0x - V2x, Euy = V0y - V2y, Euz = V0z - V2z;  // dcV/du
    double Ewx = V1x - V2x, Ewy = V1y - V2y, Ewz = V1z - V2z;  // dcV/dw
    double Fux = N0x - N2x, Fuy = N0y - N2y, Fuz = N0z - N2z;  // dn_raw/du
    double Fwx = N1x - N2x, Fwy = N1y - N2y, Fwz = N1z - N2z;  // dn_raw/dw
    double Kx  = V2x - qx,  Ky  = V2y - qy,  Kz  = V2z - qz;   // cv - q at uu=ww=0

    double u = 1.0/3.0, w = 1.0/3.0;
    double alpha = 1.0;
    for (int outer = 0; outer < 2; ++outer) {
        double du = 0.0, dw = 0.0, su = 0.0, sw = 0.0;
        for (int it = 0; it < 50; ++it) {
            double uu = u + du, ww = w + dw;
            // position term: rv = cv - q = uu*Eu + ww*Ew + K
            double rvx = uu*Eux + ww*Ewx + Kx;
            double rvy = uu*Euy + ww*Ewy + Ky;
            double rvz = uu*Euz + ww*Ewz + Kz;
            double L2v = rvx*rvx + rvy*rvy + rvz*rvz;
            double invLv = rsqrt(L2v);
            double gu = (rvx*Eux + rvy*Euy + rvz*Euz) * invLv;
            double gw = (rvx*Ewx + rvy*Ewy + rvz*Ewz) * invLv;
            // normal term: n = uu*Fu + ww*Fw + N2
            double nx = uu*Fux + ww*Fwx + N2x;
            double ny = uu*Fuy + ww*Fwy + N2y;
            double nz = uu*Fuz + ww*Fwz + N2z;
            double m2 = nx*nx + ny*ny + nz*nz;
            bool   mok = (m2 > 1e-24);           // <=> m > 1e-12
            double inv = mok ? rsqrt(m2) : 1e12; // 1/max(m,1e-12)
            double hx = nx*inv, hy = ny*inv, hz = nz*inv;
            double rnx = hx - qnx, rny = hy - qny, rnz = hz - qnz;
            double L2n = rnx*rnx + rny*rny + rnz*rnz;
            double invLn = rsqrt(L2n);
            double A_u = rnx*Fux + rny*Fuy + rnz*Fuz;
            double A_w = rnx*Fwx + rny*Fwy + rnz*Fwz;
            double B   = rnx*nx + rny*ny + rnz*nz;
            double C_u = nx*Fux + ny*Fuy + nz*Fuz;
            double C_w = nx*Fwx + ny*Fwy + nz*Fwz;
            // s = B/m^3 when m > eps else 0 (original dropped the term there)
            double s = mok ? ((B*inv)*inv)*inv : 0.0;
            double gnu = (A_u*inv - s*C_u) * invLn;
            double gnw = (A_w*inv - s*C_w) * invLn;
            gu = (gu + 0.01*gnu) * inv_denom;   // mask=1, masked-mean scaling
            gw = (gw + 0.01*gnw) * inv_denom;
            // Adagrad(lr=0.2, lr_decay=0.1)
            su += gu*gu; sw += gw*gw;
            double clr = clrtab[it];
            du -= clr * gu / (sqrt(su) + 1e-10);
            dw -= clr * gw / (sqrt(sw) + 1e-10);
        }
        u += du * alpha; w += dw * alpha;
        alpha *= 0.5;
    }
    out[NP + 2*p + 0] = (float)u;
    out[NP + 2*p + 1] = (float)w;
}

// ---------------------------------------------------------------------------
extern "C" void kernel_launch(void* const* d_in, const int* in_sizes, int n_in,
                              void* d_out, int out_size, void* d_ws, size_t ws_size,
                              hipStream_t stream) {
    const float* qV = (const float*)d_in[0];   // query_V [1,8192,3]
    const float* qN = (const float*)d_in[1];   // query_N [1,8192,3]
    const float* mV = (const float*)d_in[2];   // mesh_V  [16384,3]
    const int*   mF = (const int*)d_in[3];     // mesh_F  [16384,3] int32
    const float* mN = (const float*)d_in[4];   // mesh_N  [16384,3]
    float* out = (float*)d_out;                // fidx | vw | outlier_mask

    double* ctr      = (double*)d_ws;               // NF*4 doubles (512 KB)
    double* denom    = ctr + (size_t)NF*4;          // 1 double
    double* clrtab   = denom + 1;                   // 50 doubles
    double* pkey     = clrtab + 50;                 // NP*SPLIT doubles (128 KB)
    int*    pidx     = (int*)(pkey + (size_t)NP*SPLIT);  // NP*SPLIT ints
    int*    fidx_ws  = pidx + (size_t)NP*SPLIT;          // NP ints
    int*    valid_ws = fidx_ws + NP;                     // NP ints

    hipLaunchKernelGGL(k_centers,  dim3(NF/256),   dim3(256), 0, stream, mV, mF, ctr, clrtab);
    hipLaunchKernelGGL(k_knn_part, dim3(NG*SPLIT), dim3(256), 0, stream, qV, ctr, pkey, pidx);
    hipLaunchKernelGGL(k_finish,   dim3(NP/256),   dim3(256), 0, stream, qV, ctr, pkey, pidx,
                       out, fidx_ws, valid_ws);
    hipLaunchKernelGGL(k_denom,    dim3(1),        dim3(256), 0, stream, valid_ws, denom);
    hipLaunchKernelGGL(k_opt,      dim3(NP/256),   dim3(256), 0, stream,
                       qV, qN, mV, mF, mN, fidx_ws, valid_ws, denom, clrtab, out);
}